// Round 11
// baseline (41.073 us; speedup 1.0000x reference)
//
#include <hip/hip_runtime.h>
#include <hip/hip_bf16.h>

typedef __attribute__((ext_vector_type(8))) short short8;   // 8 bf16 (4 VGPRs)
typedef __attribute__((ext_vector_type(4))) float f32x4;    // MFMA acc

#define NPTS 131072

__device__ inline unsigned short f2bf(float f) {
    unsigned u = __float_as_uint(f);
    u = (u + 0x7FFFu + ((u >> 16) & 1u)) >> 16;   // RNE
    return (unsigned short)u;
}

__device__ inline unsigned pack2(float a, float b) {
    union { __hip_bfloat162 h; unsigned u; } v;
    v.h = __float22bfloat162_rn(float2{a, b});    // v_cvt_pk_bf16_f32 (RNE)
    return v.u;
}

// ---------------- prep (compact, 67 blocks; sections = R10-green verbatim) --
__global__ __launch_bounds__(256) void prep_kernel(
    const float* __restrict__ Ws, const float* __restrict__ bs,
    const float* __restrict__ W1, const float* __restrict__ b1,
    const float* __restrict__ W2, const float* __restrict__ W3,
    const float* __restrict__ bones,
    unsigned short* __restrict__ w1t, unsigned short* __restrict__ w2t,
    float* __restrict__ beff, unsigned short* __restrict__ w3t,
    float* __restrict__ bones4)
{
    int t = blockIdx.x * 256 + threadIdx.x;
    if (t < 4096) {
        int e = t >> 5, k = t & 31;
        float v = 0.f;
        if (k < 16) {
            for (int d = 0; d < 128; ++d) v = fmaf(Ws[k*128 + d], W1[d*128 + e], v);
        } else if (k < 19) {
            v = W1[(128 + (k - 16))*128 + e];
        }
        w1t[e*32 + k] = f2bf(v);
    } else if (t < 8192) {
        int t2 = t - 4096;
        int e = t2 >> 7, d = t2 & 127;
        w2t[e*128 + ((d & 15)*8 + (d >> 4))] = f2bf(W2[d*32 + e]);
    } else if (t < 8320) {
        int e = t - 8192;
        float v = b1[e];
        for (int d = 0; d < 128; ++d) v = fmaf(bs[d], W1[d*128 + e], v);
        beff[e] = v;
    } else if (t < 8832) {
        int i = t - 8320;
        int q = i >> 5, k = i & 31;
        int e = (k & 1)*16 + (k >> 1);        // sigma^-1(k)
        int r = e >> 3, f = e & 7;
        float v = 0.f;
        if (q < 12) {
            int r2 = q / 3, o = q - r2*3;
            if (r == r2) v = W3[f*3 + o];
        }
        w3t[q*32 + k] = f2bf(v);
    } else if (t < 8832 + 8192) {
        int i = t - 8832;                     // one bone row per thread
        float4 v;
        v.x = bones[i*3 + 0];
        v.y = bones[i*3 + 1];
        v.z = bones[i*3 + 2];
        v.w = 0.f;
        ((float4*)bones4)[i] = v;
    }
}

// ---------------- decoder: R10-green tile body, 2-tile pipelined ------------
//   per-wave LDS: H1b 16x136 bf16 = 4352 B, H2p 16x40 bf16 = 1280 B
#define WREG 5632

struct Frags {
    short8 W1f[8]; float beffv[8];
    short8 W2f[2][4]; float b2v[2];
    short8 w3f; float b3o;
};

__device__ __forceinline__ void do_tile(
    int base, const int4 ia, const int4 ib,
    float wx, float wy, float wz,
    float rw0, float rw1, float rw2, float rw3,
    const Frags& F, int q4, int l16,
    const float4* __restrict__ bn4, const float4* __restrict__ q4p,
    unsigned short* H1b, unsigned short* H2p, float* __restrict__ out)
{
    const int id[8] = { ia.x, ia.y, ia.z, ia.w, ib.x, ib.y, ib.z, ib.w };

    float w[8]; float s = 0.f;
#pragma unroll
    for (int k = 0; k < 8; ++k) {
        const float4 b = bn4[id[k]];
        const float rx = wx - b.x, ry = wy - b.y, rz = wz - b.z;
        const float dist = sqrtf(fmaf(rx,rx, fmaf(ry,ry, fmaf(rz,rz, 1e-8f))));
        w[k] = 1.0f / (dist + 1e-8f);
        s += w[k];
    }
    const float inv = 1.0f / s;

    // interp directly into the L1 A-fragment layout
    union { unsigned u[4]; short8 s8; } a1u;
    a1u.u[0] = a1u.u[1] = a1u.u[2] = a1u.u[3] = 0u;
    if (q4 < 2) {
        float acc[8] = {0.f,0.f,0.f,0.f,0.f,0.f,0.f,0.f};
#pragma unroll
        for (int k = 0; k < 8; ++k) {
            const float4 lo = q4p[id[k]*4 + q4*2 + 0];
            const float4 hi = q4p[id[k]*4 + q4*2 + 1];
            acc[0] = fmaf(w[k], lo.x, acc[0]);
            acc[1] = fmaf(w[k], lo.y, acc[1]);
            acc[2] = fmaf(w[k], lo.z, acc[2]);
            acc[3] = fmaf(w[k], lo.w, acc[3]);
            acc[4] = fmaf(w[k], hi.x, acc[4]);
            acc[5] = fmaf(w[k], hi.y, acc[5]);
            acc[6] = fmaf(w[k], hi.z, acc[6]);
            acc[7] = fmaf(w[k], hi.w, acc[7]);
        }
        a1u.u[0] = pack2(acc[0]*inv, acc[1]*inv);
        a1u.u[1] = pack2(acc[2]*inv, acc[3]*inv);
        a1u.u[2] = pack2(acc[4]*inv, acc[5]*inv);
        a1u.u[3] = pack2(acc[6]*inv, acc[7]*inv);
    } else if (q4 == 2) {
        a1u.u[0] = pack2(wx, wy);
        a1u.u[1] = pack2(wz, 0.f);
    }

    // layer 1: [16x32] @ [32x128] via 8 MFMA
    f32x4 acc1[8];
#pragma unroll
    for (int dt = 0; dt < 8; ++dt) {
        f32x4 c = { F.beffv[dt], F.beffv[dt], F.beffv[dt], F.beffv[dt] };
        acc1[dt] = __builtin_amdgcn_mfma_f32_16x16x32_bf16(a1u.s8, F.W1f[dt], c, 0, 0, 0);
    }
#pragma unroll
    for (int r = 0; r < 4; ++r) {
        union { unsigned u[4]; short8 s8; } pk;
        pk.u[0] = pack2(fmaxf(acc1[0][r],0.f), fmaxf(acc1[1][r],0.f));
        pk.u[1] = pack2(fmaxf(acc1[2][r],0.f), fmaxf(acc1[3][r],0.f));
        pk.u[2] = pack2(fmaxf(acc1[4][r],0.f), fmaxf(acc1[5][r],0.f));
        pk.u[3] = pack2(fmaxf(acc1[6][r],0.f), fmaxf(acc1[7][r],0.f));
        *(short8*)(H1b + (q4*4 + r)*136 + l16*8) = pk.s8;
    }
    __syncthreads();

    // layer 2: [16x128] @ [128x32] via 8 MFMA (pi-space K)
    f32x4 acc2[2] = { { F.b2v[0], F.b2v[0], F.b2v[0], F.b2v[0] },
                      { F.b2v[1], F.b2v[1], F.b2v[1], F.b2v[1] } };
#pragma unroll
    for (int kt = 0; kt < 4; ++kt) {
        const short8 a2 = *(const short8*)(H1b + l16*136 + kt*32 + q4*8);
        acc2[0] = __builtin_amdgcn_mfma_f32_16x16x32_bf16(a2, F.W2f[0][kt], acc2[0], 0, 0, 0);
        acc2[1] = __builtin_amdgcn_mfma_f32_16x16x32_bf16(a2, F.W2f[1][kt], acc2[1], 0, 0, 0);
    }
#pragma unroll
    for (int r = 0; r < 4; ++r) {
        unsigned p01 = pack2(fmaxf(acc2[0][r],0.f), fmaxf(acc2[1][r],0.f));
        *(unsigned*)(H2p + (q4*4 + r)*40 + l16*2) = p01;
    }
    __syncthreads();

    // layer 3: [16x32] @ [32x12] via 1 MFMA + residual
    const short8 a3 = *(const short8*)(H2p + l16*40 + q4*8);
    f32x4 c3 = { F.b3o, F.b3o, F.b3o, F.b3o };
    f32x4 o3 = __builtin_amdgcn_mfma_f32_16x16x32_bf16(a3, F.w3f, c3, 0, 0, 0);
    if (l16 < 12) {
        out[(size_t)(base + q4*4 + 0)*12 + l16] = rw0 + o3[0];
        out[(size_t)(base + q4*4 + 1)*12 + l16] = rw1 + o3[1];
        out[(size_t)(base + q4*4 + 2)*12 + l16] = rw2 + o3[2];
        out[(size_t)(base + q4*4 + 3)*12 + l16] = rw3 + o3[3];
    }
}

__global__ __launch_bounds__(256, 3) void decoder_kernel(
    const float* __restrict__ qcf, const int* __restrict__ didx,
    const float* __restrict__ dwin, const float* __restrict__ bones4,
    const unsigned short* __restrict__ w1t, const unsigned short* __restrict__ w2t,
    const float* __restrict__ beff, const float* __restrict__ b2,
    const unsigned short* __restrict__ w3t, const float* __restrict__ b3,
    float* __restrict__ out)
{
    __shared__ unsigned char lds[4 * WREG];

    const int tid  = threadIdx.x;
    const int wave = tid >> 6;
    const int lane = tid & 63;
    unsigned char* wbase = lds + wave * WREG;
    unsigned short* H1b = (unsigned short*)(wbase);
    unsigned short* H2p = (unsigned short*)(wbase + 4352);

    const int q4  = lane >> 4;
    const int l16 = lane & 15;

    const int g0    = (blockIdx.x * 4 + wave) * 2;   // two tiles per wave
    const int base0 = g0 * 16;
    const int base1 = base0 + 16;
    const int p0    = base0 + l16;
    const int p1    = base1 + l16;

    // ---- prefetch BOTH tiles' index/window loads up front ------------------
    const int4 ia0 = *(const int4*)(didx + p0*8);
    const int4 ib0 = *(const int4*)(didx + p0*8 + 4);
    const int4 ia1 = *(const int4*)(didx + p1*8);
    const int4 ib1 = *(const int4*)(didx + p1*8 + 4);
    const float wx0 = dwin[p0*3+0], wy0 = dwin[p0*3+1], wz0 = dwin[p0*3+2];
    const float wx1 = dwin[p1*3+0], wy1 = dwin[p1*3+1], wz1 = dwin[p1*3+2];

    const int o3c = l16 - (l16/3)*3;
    float rwA0=0.f, rwA1=0.f, rwA2=0.f, rwA3=0.f;
    float rwB0=0.f, rwB1=0.f, rwB2=0.f, rwB3=0.f;
    if (l16 < 12) {
        rwA0 = dwin[(size_t)(base0 + q4*4 + 0)*3 + o3c];
        rwA1 = dwin[(size_t)(base0 + q4*4 + 1)*3 + o3c];
        rwA2 = dwin[(size_t)(base0 + q4*4 + 2)*3 + o3c];
        rwA3 = dwin[(size_t)(base0 + q4*4 + 3)*3 + o3c];
        rwB0 = dwin[(size_t)(base1 + q4*4 + 0)*3 + o3c];
        rwB1 = dwin[(size_t)(base1 + q4*4 + 1)*3 + o3c];
        rwB2 = dwin[(size_t)(base1 + q4*4 + 2)*3 + o3c];
        rwB3 = dwin[(size_t)(base1 + q4*4 + 3)*3 + o3c];
    }

    // ---- hoisted weight fragments (shared by both tiles) -------------------
    Frags F;
#pragma unroll
    for (int dt = 0; dt < 8; ++dt) {
        F.W1f[dt]   = *(const short8*)(w1t + (dt*16 + l16)*32 + q4*8);
        F.beffv[dt] = beff[dt*16 + l16];
    }
#pragma unroll
    for (int et = 0; et < 2; ++et) {
        F.b2v[et] = b2[et*16 + l16];
#pragma unroll
        for (int kt = 0; kt < 4; ++kt)
            F.W2f[et][kt] = *(const short8*)(w2t + (et*16 + l16)*128 + kt*32 + q4*8);
    }
    F.w3f = *(const short8*)(w3t + l16*32 + q4*8);
    F.b3o = (l16 < 12) ? b3[o3c] : 0.f;

    const float4* __restrict__ bn4 = (const float4*)bones4;
    const float4* __restrict__ q4p = (const float4*)qcf;

    do_tile(base0, ia0, ib0, wx0, wy0, wz0, rwA0, rwA1, rwA2, rwA3,
            F, q4, l16, bn4, q4p, H1b, H2p, out);
    do_tile(base1, ia1, ib1, wx1, wy1, wz1, rwB0, rwB1, rwB2, rwB3,
            F, q4, l16, bn4, q4p, H1b, H2p, out);
}

extern "C" void kernel_launch(void* const* d_in, const int* in_sizes, int n_in,
                              void* d_out, int out_size, void* d_ws, size_t ws_size,
                              hipStream_t stream) {
    const float* qcf   = (const float*)d_in[0];
    const int*   didx  = (const int*)  d_in[1];
    const float* dwin  = (const float*)d_in[2];
    const float* bones = (const float*)d_in[3];
    // d_in[4] = K (always 8)
    const float* Ws = (const float*)d_in[5];
    const float* bs = (const float*)d_in[6];
    const float* W1 = (const float*)d_in[7];
    const float* b1 = (const float*)d_in[8];
    const float* W2 = (const float*)d_in[9];
    const float* b2 = (const float*)d_in[10];
    const float* W3 = (const float*)d_in[11];
    const float* b3 = (const float*)d_in[12];
    float* out = (float*)d_out;

    unsigned short* w1t    = (unsigned short*)d_ws;                    // 8 KB
    unsigned short* w2t    = (unsigned short*)((char*)d_ws + 8192);    // 8 KB
    float*          beff   = (float*)((char*)d_ws + 16384);            // 512 B
    unsigned short* w3t    = (unsigned short*)((char*)d_ws + 16896);   // 1 KB
    float*          bones4 = (float*)((char*)d_ws + 17920);            // 128 KB

    hipLaunchKernelGGL(prep_kernel, dim3(67), dim3(256), 0, stream,
                       Ws, bs, W1, b1, W2, W3, bones, w1t, w2t, beff, w3t, bones4);
    hipLaunchKernelGGL(decoder_kernel, dim3(1024), dim3(256), 0, stream,
                       qcf, didx, dwin, bones4, w1t, w2t, beff, b2, w3t, b3, out);
}

// Round 12
// 31.247 us; speedup vs baseline: 1.3145x; 1.3145x over previous
//
#include <hip/hip_runtime.h>

typedef __attribute__((ext_vector_type(8))) short short8;   // 8 bf16 (4 VGPRs)
typedef __attribute__((ext_vector_type(4))) float f32x4;    // MFMA acc

#define NPTS 131072

__device__ inline unsigned short f2bf(float f) {
    unsigned u = __float_as_uint(f);
    u = (u + 0x7FFFu + ((u >> 16) & 1u)) >> 16;   // RNE
    return (unsigned short)u;
}

// ---------------- prep: R4 verbatim + unroll-16 on the 128-dots -------------
// (unroll preserves the serial fmaf chain order -> identical numerics; it only
//  lets the 32 loads per group pipeline instead of serializing at ~230cyc each)
__global__ __launch_bounds__(256) void prep_kernel(
    const float* __restrict__ Ws, const float* __restrict__ bs,
    const float* __restrict__ W1, const float* __restrict__ b1,
    const float* __restrict__ W2,
    unsigned short* __restrict__ w1t, unsigned short* __restrict__ w2t,
    float* __restrict__ beff)
{
    int t = blockIdx.x * 256 + threadIdx.x;
    if (t < 4096) {                       // W1effT[e][k], k: 0..15 qcf, 16..18 win, rest 0
        int e = t >> 5, k = t & 31;
        float v = 0.f;
        if (k < 16) {
#pragma unroll 16
            for (int d = 0; d < 128; ++d) v = fmaf(Ws[k*128 + d], W1[d*128 + e], v);
        } else if (k < 19) {
            v = W1[(128 + (k - 16))*128 + e];
        }
        w1t[e*32 + k] = f2bf(v);
    } else if (t < 8192) {                // W2T[e][k] = W2[k][e]
        int t2 = t - 4096;
        int e = t2 >> 7, k = t2 & 127;
        w2t[e*128 + k] = f2bf(W2[k*32 + e]);
    } else if (t < 8320) {                // beff[e] = b1[e] + bs @ W1[0:128]
        int e = t - 8192;
        float v = b1[e];
#pragma unroll 16
        for (int d = 0; d < 128; ++d) v = fmaf(bs[d], W1[d*128 + e], v);
        beff[e] = v;
    }
}

// ---------------- main fused kernel (R4 verbatim) ---------------------------
// One 16-point tile per wave (grid 2048).
// Per-wave-private LDS region (no __syncthreads in main path):
//   X   @0     : 16 pts x 40 bf16 (stride 80 B)   = 1280 B
//   H1  @1280  : 16 pts x 136 bf16 (stride 272 B) = 4352 B
//   H2  @5632  : 16 pts x 33 f32                  = 2112 B
//   Wb  @7744  : 16x8 f32                         = 512 B
//   Ib  @8256  : 16x8 int                         = 512 B
#define WREG 8768

__global__ __launch_bounds__(256, 2) void decoder_kernel(
    const float* __restrict__ qcf, const int* __restrict__ didx,
    const float* __restrict__ dwin, const float* __restrict__ bones,
    const unsigned short* __restrict__ w1t, const unsigned short* __restrict__ w2t,
    const float* __restrict__ beff, const float* __restrict__ b2,
    const float* __restrict__ W3, const float* __restrict__ b3,
    float* __restrict__ out)
{
    __shared__ unsigned char lds[4 * WREG];
    __shared__ float sW3[27];

    const int tid = threadIdx.x;
    if (tid < 24) sW3[tid] = W3[tid];
    if (tid < 3)  sW3[24 + tid] = b3[tid];
    __syncthreads();

    const int wave = tid >> 6;
    const int lane = tid & 63;
    unsigned char* wbase = lds + wave * WREG;
    unsigned short* Xb  = (unsigned short*)(wbase);
    unsigned short* H1b = (unsigned short*)(wbase + 1280);
    float*          H2b = (float*)(wbase + 5632);
    float*          Wb  = (float*)(wbase + 7744);
    int*            Ib  = (int*)(wbase + 8256);

    const int q4  = lane >> 4;   // quarter-wave
    const int l16 = lane & 15;

    // hoisted wave-invariant weight fragments + biases
    short8 W1f[8]; float beffv[8];
#pragma unroll
    for (int dt = 0; dt < 8; ++dt) {
        W1f[dt]   = *(const short8*)(w1t + (dt*16 + l16)*32 + q4*8);
        beffv[dt] = beff[dt*16 + l16];
    }
    short8 W2f[2][4]; float b2v[2];
#pragma unroll
    for (int et = 0; et < 2; ++et) {
        b2v[et] = b2[et*16 + l16];
#pragma unroll
        for (int kt = 0; kt < 4; ++kt)
            W2f[et][kt] = *(const short8*)(w2t + (et*16 + l16)*128 + kt*32 + q4*8);
    }

    const int gw   = blockIdx.x * 4 + wave;
    const int base = gw * 16;   // one 16-point tile per wave

    // ---- IDW weights: 2 passes x (8 pts x 8 k) -----------------------------
#pragma unroll
    for (int ph = 0; ph < 2; ++ph) {
        const int pl = ph*8 + (lane >> 3);
        const int k  = lane & 7;
        const int p  = base + pl;
        const int id = didx[p*8 + k];
        const float bx = bones[id*3+0], by = bones[id*3+1], bz = bones[id*3+2];
        const float rx = dwin[p*3+0] - bx;
        const float ry = dwin[p*3+1] - by;
        const float rz = dwin[p*3+2] - bz;
        const float dist = sqrtf(fmaf(rx,rx, fmaf(ry,ry, fmaf(rz,rz, 1e-8f))));
        const float w = 1.0f / (dist + 1e-8f);
        float s = w;
        s += __shfl_xor(s, 1);
        s += __shfl_xor(s, 2);
        s += __shfl_xor(s, 4);
        Wb[pl*8 + k] = w / s;
        Ib[pl*8 + k] = id;
    }

    // ---- interp in qcf(16) space: 4 passes x 4 pts, build X bf16 -----------
#pragma unroll
    for (int ps = 0; ps < 4; ++ps) {
        const int pl = ps*4 + q4;
        const int4   i0 = *(const int4*)(Ib + pl*8);
        const int4   i1 = *(const int4*)(Ib + pl*8 + 4);
        const float4 w0 = *(const float4*)(Wb + pl*8);
        const float4 w1 = *(const float4*)(Wb + pl*8 + 4);
        float acc = 0.f;
        acc = fmaf(w0.x, qcf[i0.x*16 + l16], acc);
        acc = fmaf(w0.y, qcf[i0.y*16 + l16], acc);
        acc = fmaf(w0.z, qcf[i0.z*16 + l16], acc);
        acc = fmaf(w0.w, qcf[i0.w*16 + l16], acc);
        acc = fmaf(w1.x, qcf[i1.x*16 + l16], acc);
        acc = fmaf(w1.y, qcf[i1.y*16 + l16], acc);
        acc = fmaf(w1.z, qcf[i1.z*16 + l16], acc);
        acc = fmaf(w1.w, qcf[i1.w*16 + l16], acc);
        Xb[pl*40 + l16] = f2bf(acc);
        float wv = 0.f;
        if (l16 < 3) wv = dwin[(base + pl)*3 + l16];
        Xb[pl*40 + 16 + l16] = f2bf(wv);        // k=16..18 win, 19..31 zero
    }

    // ---- layer 1: [16 x 32] @ [32 x 128] via 8 MFMA ------------------------
    const short8 a1 = *(const short8*)(Xb + l16*40 + q4*8);
    f32x4 acc1[8];
#pragma unroll
    for (int dt = 0; dt < 8; ++dt) {
        f32x4 c = { beffv[dt], beffv[dt], beffv[dt], beffv[dt] };
        acc1[dt] = __builtin_amdgcn_mfma_f32_16x16x32_bf16(a1, W1f[dt], c, 0, 0, 0);
    }
#pragma unroll
    for (int dt = 0; dt < 8; ++dt) {
#pragma unroll
        for (int r = 0; r < 4; ++r) {
            const float h = fmaxf(acc1[dt][r], 0.f);
            H1b[(q4*4 + r)*136 + dt*16 + l16] = f2bf(h);
        }
    }

    // ---- layer 2: [16 x 128] @ [128 x 32] via 8 MFMA -----------------------
    f32x4 acc2[2] = { { b2v[0], b2v[0], b2v[0], b2v[0] },
                      { b2v[1], b2v[1], b2v[1], b2v[1] } };
#pragma unroll
    for (int kt = 0; kt < 4; ++kt) {
        const short8 a2 = *(const short8*)(H1b + l16*136 + kt*32 + q4*8);
        acc2[0] = __builtin_amdgcn_mfma_f32_16x16x32_bf16(a2, W2f[0][kt], acc2[0], 0, 0, 0);
        acc2[1] = __builtin_amdgcn_mfma_f32_16x16x32_bf16(a2, W2f[1][kt], acc2[1], 0, 0, 0);
    }
#pragma unroll
    for (int et = 0; et < 2; ++et) {
#pragma unroll
        for (int r = 0; r < 4; ++r) {
            H2b[(q4*4 + r)*33 + et*16 + l16] = fmaxf(acc2[et][r], 0.f);
        }
    }

    // ---- layer 3 (8->3 x4) + residual + store ------------------------------
#pragma unroll
    for (int i3 = 0; i3 < 3; ++i3) {
        const int g  = i3*64 + lane;      // 0..191 = 16 pts x 12
        const int pt = g / 12;
        const int q  = g - pt*12;
        const int r  = q / 3;
        const int o  = q - r*3;
        float acc = sW3[24 + o];
#pragma unroll
        for (int f = 0; f < 8; ++f)
            acc = fmaf(H2b[pt*33 + r*8 + f], sW3[f*3 + o], acc);
        const float wv = dwin[(base + pt)*3 + o];
        out[(size_t)base*12 + g] = wv + acc;
    }
}

extern "C" void kernel_launch(void* const* d_in, const int* in_sizes, int n_in,
                              void* d_out, int out_size, void* d_ws, size_t ws_size,
                              hipStream_t stream) {
    const float* qcf   = (const float*)d_in[0];
    const int*   didx  = (const int*)  d_in[1];
    const float* dwin  = (const float*)d_in[2];
    const float* bones = (const float*)d_in[3];
    // d_in[4] = K (always 8)
    const float* Ws = (const float*)d_in[5];
    const float* bs = (const float*)d_in[6];
    const float* W1 = (const float*)d_in[7];
    const float* b1 = (const float*)d_in[8];
    const float* W2 = (const float*)d_in[9];
    const float* b2 = (const float*)d_in[10];
    const float* W3 = (const float*)d_in[11];
    const float* b3 = (const float*)d_in[12];
    float* out = (float*)d_out;

    unsigned short* w1t  = (unsigned short*)d_ws;                    // 8 KB
    unsigned short* w2t  = (unsigned short*)((char*)d_ws + 8192);    // 8 KB
    float*          beff = (float*)((char*)d_ws + 16384);            // 512 B

    hipLaunchKernelGGL(prep_kernel, dim3(33), dim3(256), 0, stream,
                       Ws, bs, W1, b1, W2, w1t, w2t, beff);
    hipLaunchKernelGGL(decoder_kernel, dim3(2048), dim3(256), 0, stream,
                       qcf, didx, dwin, bones, w1t, w2t, beff, b2, W3, b3, out);
}